// Round 12
// baseline (183.405 us; speedup 1.0000x reference)
//
#include <hip/hip_runtime.h>
#include <hip/hip_bf16.h>

#define NN 8192
#define DD 256
#define BM 128
#define BN 128
#define BK 32

typedef __bf16 bf16x8 __attribute__((ext_vector_type(8)));
typedef float f32x4 __attribute__((ext_vector_type(4)));

__device__ inline void gload_lds16(const void* g, void* l) {
  __builtin_amdgcn_global_load_lds(
      (const __attribute__((address_space(1))) void*)g,
      (__attribute__((address_space(3))) void*)l, 16, 0, 0);
}

// ---------------- prep: rnorm + bf16 hi/lo split ----------------
__global__ __launch_bounds__(256) void prep_kernel(
    const float* __restrict__ Z,
    __hip_bfloat16* __restrict__ Zhi,
    __hip_bfloat16* __restrict__ Zlo,
    float* __restrict__ rnorm) {
  const int gtid = blockIdx.x * 256 + threadIdx.x;
  const int row  = gtid >> 6;          // one wave per row
  const int lane = threadIdx.x & 63;
  if (row >= NN) return;

  const float4 v = reinterpret_cast<const float4*>(Z + (size_t)row * DD)[lane];
  float ss = v.x * v.x + v.y * v.y + v.z * v.z + v.w * v.w;
#pragma unroll
  for (int off = 32; off > 0; off >>= 1) ss += __shfl_xor(ss, off);
  if (lane == 0) rnorm[row] = 1.0f / fmaxf(sqrtf(ss), 1e-8f);

  float f[4] = {v.x, v.y, v.z, v.w};
  unsigned short hi[4], lo[4];
#pragma unroll
  for (int i = 0; i < 4; ++i) {
    __hip_bfloat16 h = __float2bfloat16(f[i]);
    float hf = __bfloat162float(h);
    __hip_bfloat16 l = __float2bfloat16(f[i] - hf);
    hi[i] = *reinterpret_cast<unsigned short*>(&h);
    lo[i] = *reinterpret_cast<unsigned short*>(&l);
  }
  ushort4 hv = make_ushort4(hi[0], hi[1], hi[2], hi[3]);
  ushort4 lv = make_ushort4(lo[0], lo[1], lo[2], lo[3]);
  reinterpret_cast<ushort4*>(Zhi + (size_t)row * DD)[lane] = hv;
  reinterpret_cast<ushort4*>(Zlo + (size_t)row * DD)[lane] = lv;
}

// LDS: staging 32KB + prev-tile bf16 result 33KB + dbuf'd norms 8KB = 72.5KB
struct __attribute__((aligned(16))) SharedT {
  __hip_bfloat16 Ah[BM * BK];
  __hip_bfloat16 Al[BM * BK];
  __hip_bfloat16 Bh[BN * BK];
  __hip_bfloat16 Bl[BN * BK];
  __hip_bfloat16 tb[BM][130];   // pad 130: row AND col reads 2-way (free)
  float sRn[2][2][128];         // [buf][A=0/B=1][idx]
  int   sBt[2][2][128];
};

// --- 4-tile pipelined Gram: tile t's epilogue woven into tile t+1's K-loop --
__global__ __launch_bounds__(256, 2) void gram_kernel(
    const __hip_bfloat16* __restrict__ Zhi,
    const __hip_bfloat16* __restrict__ Zlo,
    const float* __restrict__ rnorm,
    const int* __restrict__ batch,
    float* __restrict__ outA,
    float* __restrict__ outS) {
  __shared__ SharedT sh;

  const int tid  = threadIdx.x;
  const int lane = tid & 63;
  const int wid  = tid >> 6;
  const int wr   = wid >> 1;   // 2x2 wave grid, wave owns 64x64
  const int wc   = wid & 1;
  const int lr   = lane >> 4;
  const int lc   = lane & 15;

  // XCD-bijective group id: 520 = 8*65; 4 consecutive tiles per block
  const int b = blockIdx.x;
  const int s = (b & 7) * 65 + (b >> 3);

  int prow0 = 0, pcol0 = 0;
  bool pmir = false;

  f32x4 acc[4][4];

  for (int t = 0; t < 4; ++t) {
    const int idx = 4 * s + t;
    int bcol = (int)((sqrtf(8.0f * (float)idx + 1.0f) - 1.0f) * 0.5f);
    while ((bcol + 1) * (bcol + 2) / 2 <= idx) ++bcol;
    while (bcol * (bcol + 1) / 2 > idx) --bcol;
    const int brow = idx - bcol * (bcol + 1) / 2;
    const int row0 = brow * BM, col0 = bcol * BN;
    const bool mir = (brow != bcol);
    const int cb = t & 1, pb = cb ^ 1;

    // load THIS tile's norm/batch into buffer cb (used during NEXT tile)
    if (tid < 128) {
      sh.sRn[cb][0][tid] = rnorm[row0 + tid];
      sh.sBt[cb][0][tid] = batch[row0 + tid];
    } else {
      const int t2 = tid - 128;
      sh.sRn[cb][1][t2] = rnorm[col0 + t2];
      sh.sBt[cb][1][t2] = batch[col0 + t2];
    }

#pragma unroll
    for (int m = 0; m < 4; ++m)
#pragma unroll
      for (int n = 0; n < 4; ++n) acc[m][n] = (f32x4){0, 0, 0, 0};

    for (int kt = 0; kt < DD / BK; ++kt) {
      const int k0 = kt * BK;
#pragma unroll
      for (int c = 0; c < 2; ++c) {
        const int ci  = c * 256 + tid;
        const int r   = ci >> 2;
        const int ch  = ci & 3;
        const int chg = ch ^ ((r >> 1) & 3);     // swizzle involution
        const int base = (c * 256 + wid * 64) * 16;
        const size_t ga = (size_t)(row0 + r) * DD + k0 + chg * 8;
        const size_t gb = (size_t)(col0 + r) * DD + k0 + chg * 8;
        gload_lds16(Zhi + ga, (char*)sh.Ah + base);
        gload_lds16(Zlo + ga, (char*)sh.Al + base);
        gload_lds16(Zhi + gb, (char*)sh.Bh + base);
        gload_lds16(Zlo + gb, (char*)sh.Bl + base);
      }
      __syncthreads();   // staging ready (prev kt's stores drained here too)

      // ---- 1/8 of PREVIOUS tile's epilogue: tbuf -> sigmoid/cos -> nt store
      if (t > 0) {
        // direct: 8 rows of this wave's sub-tile, 256B contiguous per instr
#pragma unroll
        for (int i = 0; i < 8; ++i) {
          const int rl = wr * 64 + kt * 8 + i;
          const int cl = wc * 64 + lane;
          const float g = __bfloat162float(sh.tb[rl][cl]);
          const float a = __builtin_amdgcn_rcpf(1.0f + __expf(-g));
          const float sv = (sh.sBt[pb][0][rl] == sh.sBt[pb][1][cl])
                               ? g * sh.sRn[pb][0][rl] * sh.sRn[pb][1][cl]
                               : 0.0f;
          const size_t o = (size_t)(prow0 + rl) * NN + (pcol0 + cl);
          __builtin_nontemporal_store(a, outA + o);
          __builtin_nontemporal_store(sv, outS + o);
        }
        if (pmir) {        // mirror: 8 cols -> 8 mirror rows, 256B contiguous
#pragma unroll
          for (int i = 0; i < 8; ++i) {
            const int cl = wc * 64 + kt * 8 + i;
            const int rl = wr * 64 + lane;
            const float g = __bfloat162float(sh.tb[rl][cl]);
            const float a = __builtin_amdgcn_rcpf(1.0f + __expf(-g));
            const float sv = (sh.sBt[pb][0][rl] == sh.sBt[pb][1][cl])
                                 ? g * sh.sRn[pb][0][rl] * sh.sRn[pb][1][cl]
                                 : 0.0f;
            const size_t o = (size_t)(pcol0 + cl) * NN + (prow0 + rl);
            __builtin_nontemporal_store(a, outA + o);
            __builtin_nontemporal_store(sv, outS + o);
          }
        }
      }

      // ---- MFMA 3-pass (hi.hi, lo.hi, hi.lo) ----
      bf16x8 fa[4], fb[4], ft[4];
#pragma unroll
      for (int m = 0; m < 4; ++m) {
        const int rA = wr * 64 + m * 16 + lc;
        const int off = rA * BK + ((lr ^ ((rA >> 1) & 3)) << 3);
        fa[m] = *reinterpret_cast<const bf16x8*>(&sh.Ah[off]);
      }
#pragma unroll
      for (int n = 0; n < 4; ++n) {
        const int rB = wc * 64 + n * 16 + lc;
        const int off = rB * BK + ((lr ^ ((rB >> 1) & 3)) << 3);
        fb[n] = *reinterpret_cast<const bf16x8*>(&sh.Bh[off]);
      }
#pragma unroll
      for (int m = 0; m < 4; ++m)
#pragma unroll
        for (int n = 0; n < 4; ++n)
          acc[m][n] = __builtin_amdgcn_mfma_f32_16x16x32_bf16(fa[m], fb[n], acc[m][n], 0, 0, 0);
#pragma unroll
      for (int m = 0; m < 4; ++m) {
        const int rA = wr * 64 + m * 16 + lc;
        const int off = rA * BK + ((lr ^ ((rA >> 1) & 3)) << 3);
        ft[m] = *reinterpret_cast<const bf16x8*>(&sh.Al[off]);
      }
#pragma unroll
      for (int m = 0; m < 4; ++m)
#pragma unroll
        for (int n = 0; n < 4; ++n)
          acc[m][n] = __builtin_amdgcn_mfma_f32_16x16x32_bf16(ft[m], fb[n], acc[m][n], 0, 0, 0);
#pragma unroll
      for (int n = 0; n < 4; ++n) {
        const int rB = wc * 64 + n * 16 + lc;
        const int off = rB * BK + ((lr ^ ((rB >> 1) & 3)) << 3);
        fb[n] = *reinterpret_cast<const bf16x8*>(&sh.Bl[off]);
      }
#pragma unroll
      for (int m = 0; m < 4; ++m)
#pragma unroll
        for (int n = 0; n < 4; ++n)
          acc[m][n] = __builtin_amdgcn_mfma_f32_16x16x32_bf16(fa[m], fb[n], acc[m][n], 0, 0, 0);
      __syncthreads();   // staging consumed; this kt's stores drained
    }

    // dump acc -> tbuf (bf16); 2-way banks; protected by barriers both sides
#pragma unroll
    for (int m = 0; m < 4; ++m)
#pragma unroll
      for (int n = 0; n < 4; ++n)
#pragma unroll
        for (int j = 0; j < 4; ++j)
          sh.tb[wr * 64 + m * 16 + lr * 4 + j][wc * 64 + n * 16 + lc] =
              __float2bfloat16(acc[m][n][j]);
    __syncthreads();
    prow0 = row0; pcol0 = col0; pmir = mir;
  }

  // tail: drain tile 3's epilogue (norms in buf 1), barrier-free
#pragma unroll 2
  for (int kt = 0; kt < 8; ++kt) {
#pragma unroll
    for (int i = 0; i < 8; ++i) {
      const int rl = wr * 64 + kt * 8 + i;
      const int cl = wc * 64 + lane;
      const float g = __bfloat162float(sh.tb[rl][cl]);
      const float a = __builtin_amdgcn_rcpf(1.0f + __expf(-g));
      const float sv = (sh.sBt[1][0][rl] == sh.sBt[1][1][cl])
                           ? g * sh.sRn[1][0][rl] * sh.sRn[1][1][cl]
                           : 0.0f;
      const size_t o = (size_t)(prow0 + rl) * NN + (pcol0 + cl);
      __builtin_nontemporal_store(a, outA + o);
      __builtin_nontemporal_store(sv, outS + o);
    }
    if (pmir) {
#pragma unroll
      for (int i = 0; i < 8; ++i) {
        const int cl = wc * 64 + kt * 8 + i;
        const int rl = wr * 64 + lane;
        const float g = __bfloat162float(sh.tb[rl][cl]);
        const float a = __builtin_amdgcn_rcpf(1.0f + __expf(-g));
        const float sv = (sh.sBt[1][0][rl] == sh.sBt[1][1][cl])
                             ? g * sh.sRn[1][0][rl] * sh.sRn[1][1][cl]
                             : 0.0f;
        const size_t o = (size_t)(pcol0 + cl) * NN + (prow0 + rl);
        __builtin_nontemporal_store(a, outA + o);
        __builtin_nontemporal_store(sv, outS + o);
      }
    }
  }
}

extern "C" void kernel_launch(void* const* d_in, const int* in_sizes, int n_in,
                              void* d_out, int out_size, void* d_ws, size_t ws_size,
                              hipStream_t stream) {
  const float* Z     = (const float*)d_in[0];
  const int*   batch = (const int*)d_in[1];
  float* out = (float*)d_out;

  __hip_bfloat16* Zhi = (__hip_bfloat16*)d_ws;
  __hip_bfloat16* Zlo = Zhi + (size_t)NN * DD;
  float* rnorm = (float*)(Zlo + (size_t)NN * DD);

  prep_kernel<<<NN / 4, 256, 0, stream>>>(Z, Zhi, Zlo, rnorm);

  // 2080 triangular tiles, 4 per block -> 520 blocks
  gram_kernel<<<dim3(520), 256, 0, stream>>>(Zhi, Zlo, rnorm, batch, out,
                                             out + (size_t)NN * NN);
}

// Round 13
// 182.603 us; speedup vs baseline: 1.0044x; 1.0044x over previous
//
#include <hip/hip_runtime.h>
#include <hip/hip_bf16.h>

#define NN 8192
#define DD 256
#define BM 128
#define BN 128
#define BK 32

typedef __bf16 bf16x8 __attribute__((ext_vector_type(8)));
typedef float f32x4 __attribute__((ext_vector_type(4)));

__device__ inline void gload_lds16(const void* g, void* l) {
  __builtin_amdgcn_global_load_lds(
      (const __attribute__((address_space(1))) void*)g,
      (__attribute__((address_space(3))) void*)l, 16, 0, 0);
}

// ---------------- prep: rnorm + bf16 hi/lo split ----------------
__global__ __launch_bounds__(256) void prep_kernel(
    const float* __restrict__ Z,
    __hip_bfloat16* __restrict__ Zhi,
    __hip_bfloat16* __restrict__ Zlo,
    float* __restrict__ rnorm) {
  const int gtid = blockIdx.x * 256 + threadIdx.x;
  const int row  = gtid >> 6;          // one wave per row
  const int lane = threadIdx.x & 63;
  if (row >= NN) return;

  const float4 v = reinterpret_cast<const float4*>(Z + (size_t)row * DD)[lane];
  float ss = v.x * v.x + v.y * v.y + v.z * v.z + v.w * v.w;
#pragma unroll
  for (int off = 32; off > 0; off >>= 1) ss += __shfl_xor(ss, off);
  if (lane == 0) rnorm[row] = 1.0f / fmaxf(sqrtf(ss), 1e-8f);

  float f[4] = {v.x, v.y, v.z, v.w};
  unsigned short hi[4], lo[4];
#pragma unroll
  for (int i = 0; i < 4; ++i) {
    __hip_bfloat16 h = __float2bfloat16(f[i]);
    float hf = __bfloat162float(h);
    __hip_bfloat16 l = __float2bfloat16(f[i] - hf);
    hi[i] = *reinterpret_cast<unsigned short*>(&h);
    lo[i] = *reinterpret_cast<unsigned short*>(&l);
  }
  ushort4 hv = make_ushort4(hi[0], hi[1], hi[2], hi[3]);
  ushort4 lv = make_ushort4(lo[0], lo[1], lo[2], lo[3]);
  reinterpret_cast<ushort4*>(Zhi + (size_t)row * DD)[lane] = hv;
  reinterpret_cast<ushort4*>(Zlo + (size_t)row * DD)[lane] = lv;
}

// LDS: staging 32KB + persistent bf16 result tile 33.8KB = 65.8KB
struct __attribute__((aligned(16))) SharedT {
  __hip_bfloat16 Ah[BM * BK];
  __hip_bfloat16 Al[BM * BK];
  __hip_bfloat16 Bh[BN * BK];
  __hip_bfloat16 Bl[BN * BK];
  __hip_bfloat16 tb[4][64][66];   // wave-private 64x64 (+2 pad) bf16 quadrant
};

__device__ __forceinline__ void kloop(
    const __hip_bfloat16* __restrict__ Zhi,
    const __hip_bfloat16* __restrict__ Zlo,
    SharedT& sh, f32x4 (&acc)[4][4],
    int row0, int col0, int tid, int wid, int wr, int wc, int lr, int lc) {
#pragma unroll
  for (int m = 0; m < 4; ++m)
#pragma unroll
    for (int n = 0; n < 4; ++n) acc[m][n] = (f32x4){0, 0, 0, 0};

  for (int kt = 0; kt < DD / BK; ++kt) {
    const int k0 = kt * BK;
#pragma unroll
    for (int c = 0; c < 2; ++c) {
      const int ci  = c * 256 + tid;
      const int r   = ci >> 2;
      const int ch  = ci & 3;
      const int chg = ch ^ ((r >> 1) & 3);     // swizzle involution
      const int base = (c * 256 + wid * 64) * 16;
      const size_t ga = (size_t)(row0 + r) * DD + k0 + chg * 8;
      const size_t gb = (size_t)(col0 + r) * DD + k0 + chg * 8;
      gload_lds16(Zhi + ga, (char*)sh.Ah + base);
      gload_lds16(Zlo + ga, (char*)sh.Al + base);
      gload_lds16(Zhi + gb, (char*)sh.Bh + base);
      gload_lds16(Zlo + gb, (char*)sh.Bl + base);
    }
    __syncthreads();

    bf16x8 fa[4], fb[4], ft[4];
#pragma unroll
    for (int m = 0; m < 4; ++m) {
      const int rA = wr * 64 + m * 16 + lc;
      const int off = rA * BK + ((lr ^ ((rA >> 1) & 3)) << 3);
      fa[m] = *reinterpret_cast<const bf16x8*>(&sh.Ah[off]);
    }
#pragma unroll
    for (int n = 0; n < 4; ++n) {
      const int rB = wc * 64 + n * 16 + lc;
      const int off = rB * BK + ((lr ^ ((rB >> 1) & 3)) << 3);
      fb[n] = *reinterpret_cast<const bf16x8*>(&sh.Bh[off]);
    }
#pragma unroll
    for (int m = 0; m < 4; ++m)
#pragma unroll
      for (int n = 0; n < 4; ++n)
        acc[m][n] = __builtin_amdgcn_mfma_f32_16x16x32_bf16(fa[m], fb[n], acc[m][n], 0, 0, 0);
#pragma unroll
    for (int m = 0; m < 4; ++m) {
      const int rA = wr * 64 + m * 16 + lc;
      const int off = rA * BK + ((lr ^ ((rA >> 1) & 3)) << 3);
      ft[m] = *reinterpret_cast<const bf16x8*>(&sh.Al[off]);
    }
#pragma unroll
    for (int m = 0; m < 4; ++m)
#pragma unroll
      for (int n = 0; n < 4; ++n)
        acc[m][n] = __builtin_amdgcn_mfma_f32_16x16x32_bf16(ft[m], fb[n], acc[m][n], 0, 0, 0);
#pragma unroll
    for (int n = 0; n < 4; ++n) {
      const int rB = wc * 64 + n * 16 + lc;
      const int off = rB * BK + ((lr ^ ((rB >> 1) & 3)) << 3);
      fb[n] = *reinterpret_cast<const bf16x8*>(&sh.Bl[off]);
    }
#pragma unroll
    for (int m = 0; m < 4; ++m)
#pragma unroll
      for (int n = 0; n < 4; ++n)
        acc[m][n] = __builtin_amdgcn_mfma_f32_16x16x32_bf16(fa[m], fb[n], acc[m][n], 0, 0, 0);
    __syncthreads();
  }
}

// dump acc -> wave-private bf16 quadrant (no barrier needed: wave-private)
__device__ __forceinline__ void dump(SharedT& sh, const f32x4 (&acc)[4][4],
                                     int wid, int lr, int lc) {
#pragma unroll
  for (int m = 0; m < 4; ++m)
#pragma unroll
    for (int n = 0; n < 4; ++n)
#pragma unroll
      for (int j = 0; j < 4; ++j)
        sh.tb[wid][m * 16 + lr * 4 + j][n * 16 + lc] =
            __float2bfloat16(acc[m][n][j]);
}

// epilogue for the tile parked in tb: wave-private reads, NT full-line stores
__device__ __forceinline__ void epi(const SharedT& sh,
                                    float* __restrict__ outA,
                                    float* __restrict__ outS,
                                    int prow0, int pcol0, bool pmir,
                                    float rA, float rB, int bA, int bB,
                                    int wid, int wr, int wc, int lane) {
  // phase A: direct rows; 256B-contiguous per instr
#pragma unroll 8
  for (int r = 0; r < 64; ++r) {
    const float g = __bfloat162float(sh.tb[wid][r][lane]);
    const float rnA = __shfl(rA, r);
    const int   btA = __shfl(bA, r);
    const float a = __builtin_amdgcn_rcpf(1.0f + __expf(-g));
    const float s = (btA == bB) ? g * rnA * rB : 0.0f;
    const size_t o = (size_t)(prow0 + wr * 64 + r) * NN + (pcol0 + wc * 64 + lane);
    __builtin_nontemporal_store(a, outA + o);
    __builtin_nontemporal_store(s, outS + o);
  }
  // phase B: mirror; 2 x 128B full lines per instr
  if (pmir) {
#pragma unroll
    for (int h = 0; h < 2; ++h) {
#pragma unroll 8
      for (int i = 0; i < 32; ++i) {
        const int c = i * 2 + (lane >> 5);   // mirror row (orig col)
        const int r = h * 32 + (lane & 31);  // orig row
        const float g = __bfloat162float(sh.tb[wid][r][c]);
        const float rnA = __shfl(rA, r);
        const int   btA = __shfl(bA, r);
        const float rnB = __shfl(rB, c);
        const int   btB = __shfl(bB, c);
        const float a = __builtin_amdgcn_rcpf(1.0f + __expf(-g));
        const float s = (btA == btB) ? g * rnA * rnB : 0.0f;
        const size_t o = (size_t)(pcol0 + wc * 64 + c) * NN + (prow0 + wr * 64 + r);
        __builtin_nontemporal_store(a, outA + o);
        __builtin_nontemporal_store(s, outS + o);
      }
    }
  }
}

// ---- odd/even phase-offset pipelined Gram (4 tiles per block) ----
__global__ __launch_bounds__(256, 2) void gram_kernel(
    const __hip_bfloat16* __restrict__ Zhi,
    const __hip_bfloat16* __restrict__ Zlo,
    const float* __restrict__ rnorm,
    const int* __restrict__ batch,
    float* __restrict__ outA,
    float* __restrict__ outS) {
  __shared__ SharedT sh;

  const int tid  = threadIdx.x;
  const int lane = tid & 63;
  const int wid  = tid >> 6;
  const int wr   = wid >> 1;
  const int wc   = wid & 1;
  const int lr   = lane >> 4;
  const int lc   = lane & 15;

  const int b = blockIdx.x;
  const int s = (b & 7) * 65 + (b >> 3);   // XCD-bijective (520 = 8*65)
  const int parity = (b >> 8) & 1;         // co-resident blocks differ (layers)

  f32x4 acc[4][4];
  int prow0 = 0, pcol0 = 0;
  bool pmir = false;
  float rA_p = 0, rB_p = 0; int bA_p = 0, bB_p = 0;

  for (int t = 0; t < 4; ++t) {
    const int idx = 4 * s + t;
    int bcol = (int)((sqrtf(8.0f * (float)idx + 1.0f) - 1.0f) * 0.5f);
    while ((bcol + 1) * (bcol + 2) / 2 <= idx) ++bcol;
    while (bcol * (bcol + 1) / 2 > idx) --bcol;
    const int brow = idx - bcol * (bcol + 1) / 2;
    const int row0 = brow * BM, col0 = bcol * BN;
    const bool mir = (brow != bcol);

    // this tile's meta -> registers (wave rows/cols)
    const float rA_c = rnorm[row0 + wr * 64 + lane];
    const float rB_c = rnorm[col0 + wc * 64 + lane];
    const int   bA_c = batch[row0 + wr * 64 + lane];
    const int   bB_c = batch[col0 + wc * 64 + lane];

    kloop(Zhi, Zlo, sh, acc, row0, col0, tid, wid, wr, wc, lr, lc);

    if (parity && t > 0)   // odd: store PREVIOUS tile (parked in tb)
      epi(sh, outA, outS, prow0, pcol0, pmir, rA_p, rB_p, bA_p, bB_p,
          wid, wr, wc, lane);

    dump(sh, acc, wid, lr, lc);
    prow0 = row0; pcol0 = col0; pmir = mir;
    rA_p = rA_c; rB_p = rB_c; bA_p = bA_c; bB_p = bB_c;

    if (!parity)           // even: store THIS tile immediately
      epi(sh, outA, outS, prow0, pcol0, pmir, rA_p, rB_p, bA_p, bB_p,
          wid, wr, wc, lane);
  }

  if (parity)              // odd: drain last tile
    epi(sh, outA, outS, prow0, pcol0, pmir, rA_p, rB_p, bA_p, bB_p,
        wid, wr, wc, lane);
}

extern "C" void kernel_launch(void* const* d_in, const int* in_sizes, int n_in,
                              void* d_out, int out_size, void* d_ws, size_t ws_size,
                              hipStream_t stream) {
  const float* Z     = (const float*)d_in[0];
  const int*   batch = (const int*)d_in[1];
  float* out = (float*)d_out;

  __hip_bfloat16* Zhi = (__hip_bfloat16*)d_ws;
  __hip_bfloat16* Zlo = Zhi + (size_t)NN * DD;
  float* rnorm = (float*)(Zlo + (size_t)NN * DD);

  prep_kernel<<<NN / 4, 256, 0, stream>>>(Z, Zhi, Zlo, rnorm);

  // 2080 triangular tiles, 4 per block -> 520 blocks
  gram_kernel<<<dim3(520), 256, 0, stream>>>(Zhi, Zlo, rnorm, batch, out,
                                             out + (size_t)NN * NN);
}

// Round 15
// 137.950 us; speedup vs baseline: 1.3295x; 1.3237x over previous
//
#include <hip/hip_runtime.h>
#include <hip/hip_bf16.h>

#define NN 8192
#define DD 256
#define BM 128
#define BN 128
#define BK 32

typedef __bf16 bf16x8 __attribute__((ext_vector_type(8)));
typedef float f32x4 __attribute__((ext_vector_type(4)));
typedef float f32x2 __attribute__((ext_vector_type(2)));

__device__ inline void gload_lds16(const void* g, void* l) {
  __builtin_amdgcn_global_load_lds(
      (const __attribute__((address_space(1))) void*)g,
      (__attribute__((address_space(3))) void*)l, 16, 0, 0);
}

// ---------------- prep: rnorm + bf16 hi/lo split ----------------
__global__ __launch_bounds__(256) void prep_kernel(
    const float* __restrict__ Z,
    __hip_bfloat16* __restrict__ Zhi,
    __hip_bfloat16* __restrict__ Zlo,
    float* __restrict__ rnorm) {
  const int gtid = blockIdx.x * 256 + threadIdx.x;
  const int row  = gtid >> 6;          // one wave per row
  const int lane = threadIdx.x & 63;
  if (row >= NN) return;

  const float4 v = reinterpret_cast<const float4*>(Z + (size_t)row * DD)[lane];
  float ss = v.x * v.x + v.y * v.y + v.z * v.z + v.w * v.w;
#pragma unroll
  for (int off = 32; off > 0; off >>= 1) ss += __shfl_xor(ss, off);
  if (lane == 0) rnorm[row] = 1.0f / fmaxf(sqrtf(ss), 1e-8f);

  float f[4] = {v.x, v.y, v.z, v.w};
  unsigned short hi[4], lo[4];
#pragma unroll
  for (int i = 0; i < 4; ++i) {
    __hip_bfloat16 h = __float2bfloat16(f[i]);
    float hf = __bfloat162float(h);
    __hip_bfloat16 l = __float2bfloat16(f[i] - hf);
    hi[i] = *reinterpret_cast<unsigned short*>(&h);
    lo[i] = *reinterpret_cast<unsigned short*>(&l);
  }
  ushort4 hv = make_ushort4(hi[0], hi[1], hi[2], hi[3]);
  ushort4 lv = make_ushort4(lo[0], lo[1], lo[2], lo[3]);
  reinterpret_cast<ushort4*>(Zhi + (size_t)row * DD)[lane] = hv;
  reinterpret_cast<ushort4*>(Zlo + (size_t)row * DD)[lane] = lv;
}

// LDS: K-loop staging tiles union'd with 4 wave-private HALF-tile (32-row)
// transpose buffers. Pad 66: dump/row-read/col-read all <=2-way (free).
struct __attribute__((aligned(16))) SharedT {
  union {
    struct {
      __hip_bfloat16 Ah[BM * BK];
      __hip_bfloat16 Al[BM * BK];
      __hip_bfloat16 Bh[BN * BK];
      __hip_bfloat16 Bl[BN * BK];
    } t;                        // 32 KB
    float tbuf[4][32][66];      // 33.8 KB, per-wave 32x64 (+2 pad)
  };
};

// ------ upper-tri Gram GEMM + barrier-free vectorized-NT dual epilogue ------
__global__ __launch_bounds__(256, 2) void gram_kernel(
    const __hip_bfloat16* __restrict__ Zhi,
    const __hip_bfloat16* __restrict__ Zlo,
    const float* __restrict__ rnorm,
    const int* __restrict__ batch,
    float* __restrict__ outA,
    float* __restrict__ outS) {
  __shared__ SharedT sh;
  __shared__ float sRnA[BM];
  __shared__ float sRnB[BN];
  __shared__ int   sBtA[BM];
  __shared__ int   sBtB[BN];

  const int tid  = threadIdx.x;
  const int lane = tid & 63;
  const int wid  = tid >> 6;
  const int wr   = wid >> 1;   // 2x2 wave grid, each wave 64x64
  const int wc   = wid & 1;

  // XCD-aware swizzle (2080 % 8 == 0 -> bijective)
  const int nb  = NN / BM;                 // 64
  const int nwg = nb * (nb + 1) / 2;       // 2080
  const int bid = blockIdx.x;
  const int idx = (bid & 7) * (nwg >> 3) + (bid >> 3);

  // triangular decode: idx -> (brow <= bcol)
  int bcol = (int)((sqrtf(8.0f * (float)idx + 1.0f) - 1.0f) * 0.5f);
  while ((bcol + 1) * (bcol + 2) / 2 <= idx) ++bcol;
  while (bcol * (bcol + 1) / 2 > idx) --bcol;
  const int brow = idx - bcol * (bcol + 1) / 2;
  const int row0 = brow * BM, col0 = bcol * BN;

  if (tid < 128) {
    sRnA[tid] = rnorm[row0 + tid];
    sBtA[tid] = batch[row0 + tid];
  } else {
    const int t = tid - 128;
    sRnB[t] = rnorm[col0 + t];
    sBtB[t] = batch[col0 + t];
  }

  f32x4 acc[4][4] = {};

  const int lr = lane >> 4;   // 0..3  (k-chunk)
  const int lc = lane & 15;   // 0..15 (row within fragment)

  for (int kt = 0; kt < DD / BK; ++kt) {
    const int k0 = kt * BK;
    // stage 4 tiles of 128x32 bf16, XOR-swizzled on the GLOBAL side
#pragma unroll
    for (int c = 0; c < 2; ++c) {
      const int ci  = c * 256 + tid;            // 16B-chunk index [0,512)
      const int r   = ci >> 2;                  // tile-local row
      const int ch  = ci & 3;
      const int chg = ch ^ ((r >> 1) & 3);      // swizzled source chunk
      const int base = (c * 256 + wid * 64) * 16;  // wave-uniform LDS byte base
      const size_t ga = (size_t)(row0 + r) * DD + k0 + chg * 8;
      const size_t gb = (size_t)(col0 + r) * DD + k0 + chg * 8;
      gload_lds16(Zhi + ga, (char*)sh.t.Ah + base);
      gload_lds16(Zlo + ga, (char*)sh.t.Al + base);
      gload_lds16(Zhi + gb, (char*)sh.t.Bh + base);
      gload_lds16(Zlo + gb, (char*)sh.t.Bl + base);
    }
    __syncthreads();   // drains vmcnt before any wave reads LDS

    // fragment-staged MFMA: peak live = fa+fb+ft = 48 VGPR
    bf16x8 fa[4], fb[4], ft[4];
#pragma unroll
    for (int m = 0; m < 4; ++m) {
      const int rA = wr * 64 + m * 16 + lc;
      const int off = rA * BK + ((lr ^ ((rA >> 1) & 3)) << 3);
      fa[m] = *reinterpret_cast<const bf16x8*>(&sh.t.Ah[off]);
    }
#pragma unroll
    for (int n = 0; n < 4; ++n) {
      const int rB = wc * 64 + n * 16 + lc;
      const int off = rB * BK + ((lr ^ ((rB >> 1) & 3)) << 3);
      fb[n] = *reinterpret_cast<const bf16x8*>(&sh.t.Bh[off]);
    }
#pragma unroll
    for (int m = 0; m < 4; ++m)
#pragma unroll
      for (int n = 0; n < 4; ++n)
        acc[m][n] = __builtin_amdgcn_mfma_f32_16x16x32_bf16(fa[m], fb[n], acc[m][n], 0, 0, 0);
#pragma unroll
    for (int m = 0; m < 4; ++m) {
      const int rA = wr * 64 + m * 16 + lc;
      const int off = rA * BK + ((lr ^ ((rA >> 1) & 3)) << 3);
      ft[m] = *reinterpret_cast<const bf16x8*>(&sh.t.Al[off]);
    }
#pragma unroll
    for (int m = 0; m < 4; ++m)
#pragma unroll
      for (int n = 0; n < 4; ++n)
        acc[m][n] = __builtin_amdgcn_mfma_f32_16x16x32_bf16(ft[m], fb[n], acc[m][n], 0, 0, 0);
#pragma unroll
    for (int n = 0; n < 4; ++n) {
      const int rB = wc * 64 + n * 16 + lc;
      const int off = rB * BK + ((lr ^ ((rB >> 1) & 3)) << 3);
      fb[n] = *reinterpret_cast<const bf16x8*>(&sh.t.Bl[off]);
    }
#pragma unroll
    for (int m = 0; m < 4; ++m)
#pragma unroll
      for (int n = 0; n < 4; ++n)
        acc[m][n] = __builtin_amdgcn_mfma_f32_16x16x32_bf16(fa[m], fb[n], acc[m][n], 0, 0, 0);
    __syncthreads();   // last one also protects tbuf overlay below
  }

  const bool mirror = (brow != bcol);

  // Barrier-free epilogue: 2 passes of 32 rows; f32x4 NT stores throughout.
  float* T = &sh.tbuf[wid][0][0];   // [32][66] f32

  for (int p = 0; p < 2; ++p) {
    // dump 32x64 (acc m = 2p, 2p+1); bank multiplicity <=2 (free)
#pragma unroll
    for (int mm = 0; mm < 2; ++mm) {
#pragma unroll
      for (int n = 0; n < 4; ++n)
#pragma unroll
        for (int j = 0; j < 4; ++j)
          T[(mm * 16 + lr * 4 + j) * 66 + n * 16 + lc] = acc[p * 2 + mm][n][j];
    }
    // (same-wave ds_write->ds_read: compiler inserts lgkmcnt; no barrier)

    // phase A: 4 rows x 64 cols per iter (16 lanes/row, f32x4 each);
    // 8 iters cover the 32x64 quadrant; 256B contiguous per 16-lane group
#pragma unroll 4
    for (int i = 0; i < 8; ++i) {
      const int r  = i * 4 + (lane >> 4);        // 0..31
      const int c4 = (lane & 15) * 4;            // 0,4,...,60
      const int rl = wr * 64 + p * 32 + r;
      const int cl = wc * 64 + c4;
      const float* tp = &T[r * 66 + c4];         // 8B aligned (66r+c4 even)
      const f32x2 g01 = *reinterpret_cast<const f32x2*>(tp);
      const f32x2 g23 = *reinterpret_cast<const f32x2*>(tp + 2);
      const float4 rnB = *reinterpret_cast<const float4*>(&sRnB[cl]);
      const int4   btB = *reinterpret_cast<const int4*>(&sBtB[cl]);
      const float rnA = sRnA[rl];
      const int   btA = sBtA[rl];
      const float gv[4] = {g01[0], g01[1], g23[0], g23[1]};
      const int   bb[4] = {btB.x, btB.y, btB.z, btB.w};
      const float rb[4] = {rnB.x, rnB.y, rnB.z, rnB.w};
      f32x4 a4, s4;
#pragma unroll
      for (int k = 0; k < 4; ++k) {
        a4[k] = __builtin_amdgcn_rcpf(1.0f + __expf(-gv[k]));
        s4[k] = (btA == bb[k]) ? gv[k] * rnA * rb[k] : 0.0f;
      }
      const size_t o = (size_t)(row0 + rl) * NN + (col0 + cl);
      __builtin_nontemporal_store(a4, reinterpret_cast<f32x4*>(outA + o));
      __builtin_nontemporal_store(s4, reinterpret_cast<f32x4*>(outS + o));
    }

    // phase B: mirrored; 8 mirror-rows x 32 cols per iter; 8-lane groups
    // write 128B full lines as f32x4
    if (mirror) {
#pragma unroll 4
      for (int i = 0; i < 8; ++i) {
        const int c  = i * 8 + (lane >> 3);      // orig col (mirror row) 0..63
        const int r4 = (lane & 7) * 4;           // orig row base 0..28
        const int rl = wr * 64 + p * 32 + r4;
        const int cl = wc * 64 + c;
        float gv[4];
#pragma unroll
        for (int k = 0; k < 4; ++k) gv[k] = T[(r4 + k) * 66 + c];  // 2-way banks
        const float4 rnA4 = *reinterpret_cast<const float4*>(&sRnA[rl]);
        const int4   btA4 = *reinterpret_cast<const int4*>(&sBtA[rl]);
        const float rnB = sRnB[cl];
        const int   btB = sBtB[cl];
        const int   ba[4] = {btA4.x, btA4.y, btA4.z, btA4.w};
        const float ra[4] = {rnA4.x, rnA4.y, rnA4.z, rnA4.w};
        f32x4 a4, s4;
#pragma unroll
        for (int k = 0; k < 4; ++k) {
          a4[k] = __builtin_amdgcn_rcpf(1.0f + __expf(-gv[k]));
          s4[k] = (ba[k] == btB) ? gv[k] * ra[k] * rnB : 0.0f;
        }
        const size_t o = (size_t)(col0 + cl) * NN + (row0 + rl);
        __builtin_nontemporal_store(a4, reinterpret_cast<f32x4*>(outA + o));
        __builtin_nontemporal_store(s4, reinterpret_cast<f32x4*>(outS + o));
      }
    }
  }
}

extern "C" void kernel_launch(void* const* d_in, const int* in_sizes, int n_in,
                              void* d_out, int out_size, void* d_ws, size_t ws_size,
                              hipStream_t stream) {
  const float* Z     = (const float*)d_in[0];
  const int*   batch = (const int*)d_in[1];
  float* out = (float*)d_out;

  __hip_bfloat16* Zhi = (__hip_bfloat16*)d_ws;
  __hip_bfloat16* Zlo = Zhi + (size_t)NN * DD;
  float* rnorm = (float*)(Zlo + (size_t)NN * DD);

  prep_kernel<<<NN / 4, 256, 0, stream>>>(Z, Zhi, Zlo, rnorm);

  const int nb = NN / BM;                 // 64
  const int nblocks = nb * (nb + 1) / 2;  // 2080
  gram_kernel<<<dim3(nblocks), 256, 0, stream>>>(Zhi, Zlo, rnorm, batch, out,
                                                 out + (size_t)NN * NN);
}